// Round 14
// baseline (311214.893 us; speedup 1.0000x reference)
//
#include <hip/hip_runtime.h>
#include <hip/hip_fp8.h>

#define DIMD 128
#define EPSV 1e-5f

typedef _Float16 f16;
typedef f16 f16x2 __attribute__((ext_vector_type(2)));
typedef f16 f16x8 __attribute__((ext_vector_type(8)));
typedef float f32x2 __attribute__((ext_vector_type(2)));
typedef float f32x4 __attribute__((ext_vector_type(4)));

// ---------------- edge-index dtype probe (int64 stored vs int32) ----------
__global__ void k_detect(const int* __restrict__ ei, int nchk, int* __restrict__ mode) {
    __shared__ int any;
    if (threadIdx.x == 0) any = 0;
    __syncthreads();
    for (int i = threadIdx.x; i < nchk; i += 256)
        if (ei[2 * i + 1] != 0) any = 1;   // benign race
    __syncthreads();
    if (threadIdx.x == 0) *mode = any ? 0 : 1;  // 1 => data is int64 pairs
}

__device__ __forceinline__ int load_src(const int* ei, int e, int E, int m) {
    return m ? ei[2 * e] : ei[e];
}
__device__ __forceinline__ int load_dst(const int* ei, int e, int E, int m) {
    return m ? ei[2 * (E + e)] : ei[E + e];
}

// ---------------- latent -> fp16 copy -------------------------------------
__global__ void k_prep(const float2* __restrict__ lat, f16x2* __restrict__ lat16,
                       int total2) {
    int i = blockIdx.x * 256 + threadIdx.x;
    if (i < total2) {
        float2 v = lat[i];
        f16x2 o = {(f16)v.x, (f16)v.y};
        lat16[i] = o;
    }
}

// ---------------- W0 -> f16 transposed: Wt[j][k] = W[k][j] ----------------
__global__ void k_w0(const float* __restrict__ W, f16* __restrict__ Wt) {
    int idx = blockIdx.x * 256 + threadIdx.x;  // 16384
    int j = idx >> 7, k = idx & 127;
    Wt[idx] = (f16)W[k * 128 + j];
}

// ---------------- rank + histogram (single atomic pass) --------------------
__global__ void k_rank(const int* __restrict__ ei, int* __restrict__ rank,
                       int* __restrict__ cnt, const int* __restrict__ modep, int E) {
    int e = blockIdx.x * 256 + threadIdx.x;
    if (e < E) {
        int m = *modep;
        int d = load_dst(ei, e, E, m);
        rank[e] = atomicAdd(&cnt[d], 1);
    }
}

// ---------------- 3-kernel exclusive scan of cnt -> offs -------------------
__global__ void k_scanA(const int* __restrict__ cnt, int* __restrict__ offs,
                        int* __restrict__ bsum, int N) {
    __shared__ int sh[256];
    int tid = threadIdx.x;
    int i = blockIdx.x * 256 + tid;
    int v = (i < N) ? cnt[i] : 0;
    sh[tid] = v;
    __syncthreads();
    for (int off = 1; off < 256; off <<= 1) {
        int t = (tid >= off) ? sh[tid - off] : 0;
        __syncthreads();
        sh[tid] += t;
        __syncthreads();
    }
    if (i < N) offs[i] = sh[tid] - v;  // exclusive
    if (tid == 255) bsum[blockIdx.x] = sh[255];
}

__global__ void k_scanB(int* __restrict__ bsum, int* __restrict__ bbase, int NB) {
    __shared__ int sh[256];
    int tid = threadIdx.x;
    int v = (tid < NB) ? bsum[tid] : 0;
    sh[tid] = v;
    __syncthreads();
    for (int off = 1; off < 256; off <<= 1) {
        int t = (tid >= off) ? sh[tid - off] : 0;
        __syncthreads();
        sh[tid] += t;
        __syncthreads();
    }
    if (tid < NB) bbase[tid] = sh[tid] - v;
}

__global__ void k_scanC(const int* __restrict__ cnt, int* __restrict__ offs,
                        const int* __restrict__ bbase, int N) {
    int i = blockIdx.x * 256 + threadIdx.x;
    if (i < N) {
        int v = offs[i] + bbase[blockIdx.x];
        offs[i] = v;
        if (i == N - 1) offs[N] = v + cnt[i];
    }
}

// ------- CSR fill (atomic-free): csr = {src, f32 w/16} --------------------
__global__ void k_fill(const int* __restrict__ ei, const float* __restrict__ ew,
                       const int* __restrict__ offs, const int* __restrict__ rank,
                       int2* __restrict__ csr, const int* __restrict__ modep, int E) {
    int e = blockIdx.x * 256 + threadIdx.x;
    if (e < E) {
        int m = *modep;
        int s = load_src(ei, e, E, m);
        int d = load_dst(ei, e, E, m);
        int pos = offs[d] + rank[e];
        csr[pos] = make_int2(s, __float_as_int(ew[e] * 0.0625f));
    }
}

// ---------------- degree from CSR (coalesced) -> dinv ----------------------
__global__ __launch_bounds__(256) void k_deg(const int2* __restrict__ csr,
                                             const int* __restrict__ offs,
                                             float* __restrict__ dinv, int N, int nwaves) {
    int lane = threadIdx.x & 63;
    int wid = blockIdx.x * 4 + (threadIdx.x >> 6);
    for (int n = wid; n < N; n += nwaves) {
        int kb = offs[n], ke = offs[n + 1];
        float s = 0.f;
        for (int e = kb + lane; e < ke; e += 64) s += __int_as_float(csr[e].y);
        for (int off = 32; off; off >>= 1) s += __shfl_down(s, off);
        if (lane == 0) dinv[n] = rsqrtf(16.0f * s + 1.0f);
    }
}

// --- MFMA GEMM 64-row (production layer 0; round-11-passing) --------------
__global__ __launch_bounds__(256) void k_gemm_mfma(const f16x8* __restrict__ X,
                                                   const f16* __restrict__ Wt,
                                                   const float* __restrict__ cb,
                                                   const float* __restrict__ dinv,
                                                   unsigned* __restrict__ Y8, int N) {
    __shared__ __align__(16) char lds[32768];
    int tid = threadIdx.x;
#pragma unroll
    for (int it = 0; it < 8; ++it) {
        int c = tid + it * 256;
        int j = c >> 4, k16 = c & 15;
        int dst = j * 256 + ((k16 * 16) ^ ((j & 7) << 4));
        *(f16x8*)(lds + dst) = ((const f16x8*)Wt)[c];
    }
    __syncthreads();
    int lane = tid & 63;
    int wv = tid >> 6;
    int kq = lane >> 4;
    int mrow = blockIdx.x * 64 + wv * 16 + (lane & 15);
    int mc = mrow < N ? mrow : N - 1;
    f16x8 xf[4];
#pragma unroll
    for (int kt = 0; kt < 4; ++kt) xf[kt] = X[(size_t)mc * 16 + kt * 4 + kq];
    float dv = dinv[mc] * 16.0f;
    bool wr = (mrow < N);
#pragma unroll
    for (int jt = 0; jt < 8; ++jt) {
        f32x4 acc = {0.f, 0.f, 0.f, 0.f};
        int j = jt * 16 + (lane & 15);
        int rb = j * 256;
        int sw = (j & 7) << 4;
#pragma unroll
        for (int kt = 0; kt < 4; ++kt) {
            f16x8 wf = *(const f16x8*)(lds + rb + ((kt * 64 + kq * 16) ^ sw));
            acc = __builtin_amdgcn_mfma_f32_16x16x32_f16(wf, xf[kt], acc, 0, 0, 0);
        }
        float4 c4 = {0.f, 0.f, 0.f, 0.f};
        if (cb) c4 = ((const float4*)cb)[jt * 4 + kq];
        if (wr) {
            __hip_fp8x2_storage_t lo = __hip_cvt_float2_to_fp8x2(
                make_float2((acc[0] + c4.x) * dv, (acc[1] + c4.y) * dv),
                __HIP_SATFINITE, __HIP_E4M3);
            __hip_fp8x2_storage_t hi = __hip_cvt_float2_to_fp8x2(
                make_float2((acc[2] + c4.z) * dv, (acc[3] + c4.w) * dv),
                __HIP_SATFINITE, __HIP_E4M3);
            Y8[(size_t)mrow * 32 + jt * 4 + kq] = (unsigned)lo | ((unsigned)hi << 16);
        }
    }
}

// --- MFMA GEMM 128-row (PROBE ONLY: writes scratch buffer) ----------------
__global__ __launch_bounds__(256) void k_gemm_mfma128(const f16x8* __restrict__ X,
                                                      const f16* __restrict__ Wt,
                                                      const float* __restrict__ cb,
                                                      const float* __restrict__ dinv,
                                                      unsigned* __restrict__ Y8, int N) {
    __shared__ __align__(16) char lds[32768];
    int tid = threadIdx.x;
#pragma unroll
    for (int it = 0; it < 8; ++it) {
        int c = tid + it * 256;
        int j = c >> 4, k16 = c & 15;
        int dst = j * 256 + ((k16 * 16) ^ ((j & 7) << 4));
        *(f16x8*)(lds + dst) = ((const f16x8*)Wt)[c];
    }
    __syncthreads();
    int lane = tid & 63;
    int wv = tid >> 6;
    int kq = lane >> 4;
#pragma unroll
    for (int half = 0; half < 2; ++half) {
        int mrow = blockIdx.x * 128 + half * 64 + wv * 16 + (lane & 15);
        int mc = mrow < N ? mrow : N - 1;
        f16x8 xf[4];
#pragma unroll
        for (int kt = 0; kt < 4; ++kt) xf[kt] = X[(size_t)mc * 16 + kt * 4 + kq];
        float dv = dinv[mc] * 16.0f;
        bool wr = (mrow < N);
#pragma unroll
        for (int jt = 0; jt < 8; ++jt) {
            f32x4 acc = {0.f, 0.f, 0.f, 0.f};
            int j = jt * 16 + (lane & 15);
            int rb = j * 256;
            int sw = (j & 7) << 4;
#pragma unroll
            for (int kt = 0; kt < 4; ++kt) {
                f16x8 wf = *(const f16x8*)(lds + rb + ((kt * 64 + kq * 16) ^ sw));
                acc = __builtin_amdgcn_mfma_f32_16x16x32_f16(wf, xf[kt], acc, 0, 0, 0);
            }
            float4 c4 = {0.f, 0.f, 0.f, 0.f};
            if (cb) c4 = ((const float4*)cb)[jt * 4 + kq];
            if (wr) {
                __hip_fp8x2_storage_t lo = __hip_cvt_float2_to_fp8x2(
                    make_float2((acc[0] + c4.x) * dv, (acc[1] + c4.y) * dv),
                    __HIP_SATFINITE, __HIP_E4M3);
                __hip_fp8x2_storage_t hi = __hip_cvt_float2_to_fp8x2(
                    make_float2((acc[2] + c4.z) * dv, (acc[3] + c4.w) * dv),
                    __HIP_SATFINITE, __HIP_E4M3);
                Y8[(size_t)mrow * 32 + jt * 4 + kq] = (unsigned)lo | ((unsigned)hi << 16);
            }
        }
    }
}

// --- GEMM (VALU, known-good production): y8 = fp8(16*dinv*(X16@W + cb)) ---
__global__ __launch_bounds__(256) void k_gemm(const f16x2* __restrict__ X16,
                                              const float* __restrict__ W,
                                              const float* __restrict__ cb,
                                              const float* __restrict__ dinv,
                                              unsigned* __restrict__ Y8, int N) {
    __shared__ float Wl[64 * 128];
    __shared__ float xl[8 * 64];
    int tid = threadIdx.x;
    int nl = tid >> 5, jg = tid & 31;
    int base = blockIdx.x * 8;
    float4 acc = {0.f, 0.f, 0.f, 0.f};
    for (int chunk = 0; chunk < 2; ++chunk) {
        int kc = chunk * 64;
        const float4* Wg = (const float4*)(W + (size_t)kc * 128);
#pragma unroll
        for (int r = 0; r < 8; r++) ((float4*)Wl)[r * 256 + tid] = Wg[r * 256 + tid];
        {
            int rr = tid >> 5;
            int kk = (tid & 31) * 2;
            int row = base + rr;
            float2 v = {0.f, 0.f};
            if (row < N) {
                f16x2 hv = X16[(size_t)row * 64 + (kc >> 1) + (tid & 31)];
                v.x = (float)hv.x;
                v.y = (float)hv.y;
            }
            xl[rr * 64 + kk] = v.x;
            xl[rr * 64 + kk + 1] = v.y;
        }
        __syncthreads();
#pragma unroll 8
        for (int k = 0; k < 64; k++) {
            float xv = xl[nl * 64 + k];
            float4 w4 = ((const float4*)Wl)[k * 32 + jg];
            acc.x += xv * w4.x;
            acc.y += xv * w4.y;
            acc.z += xv * w4.z;
            acc.w += xv * w4.w;
        }
        __syncthreads();
    }
    if (cb) {
        float4 c4 = ((const float4*)cb)[jg];
        acc.x += c4.x; acc.y += c4.y; acc.z += c4.z; acc.w += c4.w;
    }
    int n = base + nl;
    if (n < N) {
        float sc = dinv[n] * 16.0f;
        __hip_fp8x2_storage_t lo = __hip_cvt_float2_to_fp8x2(
            make_float2(acc.x * sc, acc.y * sc), __HIP_SATFINITE, __HIP_E4M3);
        __hip_fp8x2_storage_t hi = __hip_cvt_float2_to_fp8x2(
            make_float2(acc.z * sc, acc.w * sc), __HIP_SATFINITE, __HIP_E4M3);
        Y8[(size_t)n * 32 + jg] = (unsigned)lo | ((unsigned)hi << 16);
    }
}

// ------- full-buffer fp8 compare, region-split into two slots --------------
// excess = |a-b| - (0.12*max + 2); region = (dword >= splitDword).
__global__ __launch_bounds__(256) void k_cmp2(const unsigned* __restrict__ a,
                                              const unsigned* __restrict__ b,
                                              float* __restrict__ slotLo,
                                              float* __restrict__ slotHi,
                                              int splitDword, int total) {
    int i = blockIdx.x * 256 + threadIdx.x;
    float excess = -1.f;
    int hi_region = 0;
    if (i < total) {
        hi_region = (i >= splitDword) ? 1 : 0;
        unsigned da = a[i], db = b[i];
        if (da != db) {
            f32x2 al = __builtin_amdgcn_cvt_pk_f32_fp8(da, false);
            f32x2 ah = __builtin_amdgcn_cvt_pk_f32_fp8(da, true);
            f32x2 bl = __builtin_amdgcn_cvt_pk_f32_fp8(db, false);
            f32x2 bh = __builtin_amdgcn_cvt_pk_f32_fp8(db, true);
            float e;
            e = fabsf(al.x - bl.x) - (0.12f * fmaxf(fabsf(al.x), fabsf(bl.x)) + 2.f);
            excess = fmaxf(excess, e);
            e = fabsf(al.y - bl.y) - (0.12f * fmaxf(fabsf(al.y), fabsf(bl.y)) + 2.f);
            excess = fmaxf(excess, e);
            e = fabsf(ah.x - bh.x) - (0.12f * fmaxf(fabsf(ah.x), fabsf(bh.x)) + 2.f);
            excess = fmaxf(excess, e);
            e = fabsf(ah.y - bh.y) - (0.12f * fmaxf(fabsf(ah.y), fabsf(bh.y)) + 2.f);
            excess = fmaxf(excess, e);
        }
    }
#pragma unroll
    for (int off = 32; off; off >>= 1) excess = fmaxf(excess, __shfl_down(excess, off));
    // split at wave-aligned boundary -> hi_region uniform per wave
    if ((threadIdx.x & 63) == 0 && excess > 0.f)
        atomicMax((int*)(hi_region ? slotHi : slotLo), __float_as_int(excess));
}

// Verdict: spin-encode 6 flags (10/20/40/80/160/320 ms @ 100 MHz wall clock)
// dbg[0]=L1 n<16384, dbg[1]=L1 n>=16384, dbg[2]=L2 lo, dbg[3]=L2 hi,
// dbg[4]=MFMA-repro (race detect), dbg[5]=VALU-repro (calibration)
__global__ void k_verdict(const float* __restrict__ dbg, int* __restrict__ sink) {
    if (threadIdx.x == 0) {
        long long t = 0;
        if (dbg[0] > 0.5f) t += 1000000LL;
        if (dbg[1] > 0.5f) t += 2000000LL;
        if (dbg[2] > 0.5f) t += 4000000LL;
        if (dbg[3] > 0.5f) t += 8000000LL;
        if (dbg[4] > 0.5f) t += 16000000LL;
        if (dbg[5] > 0.5f) t += 32000000LL;
        int spins = 0;
        if (t) {
            long long t0 = wall_clock64();
            while (wall_clock64() - t0 < t) spins++;
        }
        sink[0] = spins;
    }
}

// ------- aggregation: t = dinv*(sum w'*y8[src] + y8[n]/16) + b (...) ------
__global__ __launch_bounds__(256) void k_aggr(
    const unsigned short* __restrict__ y8, const f16x2* __restrict__ lat16,
    const int2* __restrict__ csr, const int* __restrict__ offs,
    const float* __restrict__ dinv, const float* __restrict__ bias,
    f16x2* __restrict__ T16, float* __restrict__ gsum, float* __restrict__ gsq,
    int N, int relu, int nwaves) {
    __shared__ float ssum[128], ssq[128];
    int tid = threadIdx.x;
    if (tid < 128) { ssum[tid] = 0.f; ssq[tid] = 0.f; }
    __syncthreads();
    unsigned lane = tid & 63;
    int wid = blockIdx.x * 4 + (tid >> 6);
    float2 b2 = ((const float2*)bias)[lane];
    float2 ts = {0.f, 0.f}, tq = {0.f, 0.f};
    for (int n = wid; n < N; n += nwaves) {
        int kb = offs[n], ke = offs[n + 1];
        float2 acc = {0.f, 0.f};
        for (int b0 = kb; b0 < ke; b0 += 64) {
            int e = b0 + (int)lane;
            int2 v = make_int2(0, 0);
            if (e < ke) v = csr[e];
            int cnt8 = (min(64, ke - b0) + 7) & ~7;  // wave-uniform
            for (int t0 = 0; t0 < cnt8; t0 += 8) {
#pragma unroll
                for (int u = 0; u < 8; u++) {
                    int t = t0 + u;
                    unsigned ss = (unsigned)__builtin_amdgcn_readlane(v.x, t);
                    float ww = __uint_as_float(
                        (unsigned)__builtin_amdgcn_readlane(v.y, t));
                    unsigned r = y8[(ss << 6) | lane];   // 32-bit voffset
                    f32x2 yv = __builtin_amdgcn_cvt_pk_f32_fp8(r, false);
                    acc.x += ww * yv.x;
                    acc.y += ww * yv.y;
                }
            }
        }
        f32x2 sv = __builtin_amdgcn_cvt_pk_f32_fp8(
            (unsigned)y8[((unsigned)n << 6) | lane], false);
        float dv = dinv[n];
        acc.x = (acc.x + 0.0625f * sv.x) * dv + b2.x;
        acc.y = (acc.y + 0.0625f * sv.y) * dv + b2.y;
        if (relu) { acc.x = fmaxf(acc.x, 0.f); acc.y = fmaxf(acc.y, 0.f); }
        f16x2 lv = lat16[((unsigned)n << 6) | lane];
        acc.x += (float)lv.x;
        acc.y += (float)lv.y;
        f16x2 to = {(f16)acc.x, (f16)acc.y};
        T16[((unsigned)n << 6) | lane] = to;
        ts.x += acc.x; ts.y += acc.y;
        tq.x += acc.x * acc.x; tq.y += acc.y * acc.y;
    }
    atomicAdd(&ssum[lane * 2], ts.x);
    atomicAdd(&ssum[lane * 2 + 1], ts.y);
    atomicAdd(&ssq[lane * 2], tq.x);
    atomicAdd(&ssq[lane * 2 + 1], tq.y);
    __syncthreads();
    if (tid < 128) {
        int copy = blockIdx.x & 31;
        atomicAdd(&gsum[copy * 128 + tid], ssum[tid]);
        atomicAdd(&gsq[copy * 128 + tid], ssq[tid]);
    }
}

// ------- fused BN stats + f32 Wf + f16-transposed Wt16f + cW --------------
__global__ void k_post(const float* __restrict__ gsum, const float* __restrict__ gsq,
                       const float* __restrict__ gamma, const float* __restrict__ beta,
                       const float* __restrict__ W, float* __restrict__ A,
                       float* __restrict__ C, float* __restrict__ Wf,
                       f16* __restrict__ Wt16f, float* __restrict__ cW, int N) {
    __shared__ float As[128], Cs[128];
    int tid = threadIdx.x;  // 256
    if (tid < 128) {
        float s = 0.f, q = 0.f;
        for (int c = 0; c < 32; c++) { s += gsum[c * 128 + tid]; q += gsq[c * 128 + tid]; }
        float mean = s / (float)N;
        float var = q / (float)N - mean * mean;
        float a = gamma[tid] * rsqrtf(var + EPSV);
        float cc = beta[tid] - a * mean;
        As[tid] = a; Cs[tid] = cc;
        A[tid] = a; C[tid] = cc;
    }
    __syncthreads();
    if (W) {
        for (int i4 = tid; i4 < 4096; i4 += 256) {
            int k = i4 >> 5;
            float a = As[k];
            float4 w = ((const float4*)W)[i4];
            float4 o;
            o.x = a * w.x; o.y = a * w.y; o.z = a * w.z; o.w = a * w.w;
            ((float4*)Wf)[i4] = o;
        }
        for (int idx = tid; idx < 16384; idx += 256) {
            int j = idx >> 7, k = idx & 127;
            Wt16f[idx] = (f16)(As[k] * W[k * 128 + j]);   // Wt[j][k] = A[k]*W[k][j]
        }
        if (tid < 128) {
            float acc = 0.f;
            for (int k = 0; k < 128; k++) acc += Cs[k] * W[k * 128 + tid];
            cW[tid] = acc;
        }
    }
}

// ---------------- final normalize of layer-2 output ------------------------
__global__ void k_bnorm(const f16x2* __restrict__ T16, const float* __restrict__ A,
                        const float* __restrict__ C, float2* __restrict__ out, int total2) {
    int i = blockIdx.x * 256 + threadIdx.x;
    if (i < total2) {
        int c = i & 63;
        f16x2 t = T16[i];
        float2 a = ((const float2*)A)[c];
        float2 cc = ((const float2*)C)[c];
        float2 r;
        r.x = a.x * (float)t.x + cc.x;
        r.y = a.y * (float)t.y + cc.y;
        out[i] = r;
    }
}

extern "C" void kernel_launch(void* const* d_in, const int* in_sizes, int n_in,
                              void* d_out, int out_size, void* d_ws, size_t ws_size,
                              hipStream_t stream) {
    const float* latent = (const float*)d_in[0];
    const int* ei = (const int*)d_in[1];
    const float* ew = (const float*)d_in[2];
    const float* Ws = (const float*)d_in[3];
    const float* bs = (const float*)d_in[4];
    const float* gammas = (const float*)d_in[5];
    const float* betas = (const float*)d_in[6];
    float* out = (float*)d_out;

    const int N = in_sizes[0] / DIMD;
    const int E = in_sizes[1] / 2;
    const int NB = (N + 255) / 256;
    const int Npad = (N + 255) & ~255;

    char* p = (char*)d_ws;
    auto alloc = [&](size_t b) -> char* {
        char* r = p;
        p += (b + 255) & ~(size_t)255;
        return r;
    };
    // ---- zero-initialized region (must stay first & contiguous) ----
    int* cnt = (int*)alloc((size_t)Npad * 4);
    float* gstats = (float*)alloc((size_t)3 * 2 * 32 * 128 * 4);  // [layer][sum/sq][copy][j]
    float* dbg = (float*)alloc(256);
    size_t zbytes = (size_t)(p - (char*)d_ws);
    // ---- rest ----
    int* mode = (int*)alloc(256);
    float* dinv = (float*)alloc((size_t)N * 4);
    int* offs = (int*)alloc((size_t)(N + 1) * 4);
    int* bsum = (int*)alloc(256 * 4);
    int* bbase = (int*)alloc(256 * 4);
    float* A = (float*)alloc(128 * 4);
    float* C = (float*)alloc(128 * 4);
    float* cW = (float*)alloc(128 * 4);
    float* Wf = (float*)alloc((size_t)128 * 128 * 4);
    f16* Wt16 = (f16*)alloc((size_t)128 * 128 * 2);            // W0 transposed (layer-0 MFMA)
    f16* Wt16f = (f16*)alloc((size_t)128 * 128 * 2);           // folded transposed (probe)
    int* rank = (int*)alloc((size_t)E * 4);                    // reused as probe scratch
    int2* csr = (int2*)alloc((size_t)E * 8);
    unsigned* bufY8 = (unsigned*)alloc((size_t)N * DIMD);      // y (fp8 e4m3, x16)
    unsigned* bufY8m = (unsigned*)alloc((size_t)N * DIMD);     // probe MFMA y8
    f16x2* lat16 = (f16x2*)alloc((size_t)N * DIMD * 2);        // latent (fp16)
    f16x2* bufB16 = (f16x2*)alloc((size_t)N * DIMD * 2);       // t (fp16)

    hipMemsetAsync(d_ws, 0, zbytes, stream);

    int nchk = E < 4096 ? E : 4096;
    int total2 = N * (DIMD / 2);
    k_detect<<<1, 256, 0, stream>>>(ei, nchk, mode);
    k_prep<<<(total2 + 255) / 256, 256, 0, stream>>>((const float2*)latent, lat16, total2);
    k_w0<<<64, 256, 0, stream>>>(Ws, Wt16);
    k_rank<<<(E + 255) / 256, 256, 0, stream>>>(ei, rank, cnt, mode, E);
    k_scanA<<<NB, 256, 0, stream>>>(cnt, offs, bsum, N);
    k_scanB<<<1, 256, 0, stream>>>(bsum, bbase, NB);
    k_scanC<<<NB, 256, 0, stream>>>(cnt, offs, bbase, N);
    k_fill<<<(E + 255) / 256, 256, 0, stream>>>(ei, ew, offs, rank, csr, mode, E);
    k_deg<<<512, 256, 0, stream>>>(csr, offs, dinv, N, 2048);
    // rank[] is dead from here on -> reuse as probe scratch (E = N*32 dwords)
    unsigned* scr = (unsigned*)rank;

    int totalD = N * 32;
    int splitD = 16384 * 32;  // node 16384 boundary (wave-aligned)
    const f16x2* gin = lat16;
    for (int i = 0; i < 3; i++) {
        if (i == 0) {
            k_gemm_mfma<<<(N + 63) / 64, 256, 0, stream>>>((const f16x8*)gin, Wt16,
                                                           nullptr, dinv, bufY8, N);
        } else {
            k_gemm<<<(N + 7) / 8, 256, 0, stream>>>(gin, Wf, cW, dinv, bufY8, N);
            if (i == 1) {
                // VALU determinism calibration
                k_gemm<<<(N + 7) / 8, 256, 0, stream>>>(gin, Wf, cW, dinv, scr, N);
                k_cmp2<<<(totalD + 255) / 256, 256, 0, stream>>>(bufY8, scr, dbg + 5,
                                                                 dbg + 5, totalD, totalD);
                // MFMA x2: determinism check
                k_gemm_mfma128<<<(N + 127) / 128, 256, 0, stream>>>(
                    (const f16x8*)gin, Wt16f, cW, dinv, bufY8m, N);
                k_gemm_mfma128<<<(N + 127) / 128, 256, 0, stream>>>(
                    (const f16x8*)gin, Wt16f, cW, dinv, scr, N);
                k_cmp2<<<(totalD + 255) / 256, 256, 0, stream>>>(bufY8m, scr, dbg + 4,
                                                                 dbg + 4, totalD, totalD);
                // L1 range-split MFMA-vs-VALU
                k_cmp2<<<(totalD + 255) / 256, 256, 0, stream>>>(bufY8, bufY8m, dbg + 0,
                                                                 dbg + 1, splitD, totalD);
            } else {
                k_gemm_mfma128<<<(N + 127) / 128, 256, 0, stream>>>(
                    (const f16x8*)gin, Wt16f, cW, dinv, bufY8m, N);
                k_cmp2<<<(totalD + 255) / 256, 256, 0, stream>>>(bufY8, bufY8m, dbg + 2,
                                                                 dbg + 3, splitD, totalD);
            }
        }
        float* gsum_i = gstats + (size_t)i * 2 * 32 * 128;
        float* gsq_i = gsum_i + 32 * 128;
        k_aggr<<<2048, 256, 0, stream>>>((const unsigned short*)bufY8, lat16, csr, offs,
                                         dinv, bs + i * DIMD, bufB16, gsum_i, gsq_i, N,
                                         (i != 1) ? 1 : 0, 8192);
        const float* Wnext = (i < 2) ? (Ws + (size_t)(i + 1) * DIMD * DIMD) : nullptr;
        k_post<<<1, 256, 0, stream>>>(gsum_i, gsq_i, gammas + i * DIMD, betas + i * DIMD,
                                      Wnext, A, C, Wf, Wt16f, cW, N);
        if (i < 2) gin = bufB16;  // next GEMM consumes un-normalized t (fp16)
    }
    k_verdict<<<1, 64, 0, stream>>>(dbg, (int*)(dbg + 8));
    k_bnorm<<<(total2 + 255) / 256, 256, 0, stream>>>(bufB16, A, C, (float2*)out, total2);
}

// Round 15
// 387.912 us; speedup vs baseline: 802.2817x; 802.2817x over previous
//
#include <hip/hip_runtime.h>
#include <hip/hip_fp8.h>

#define DIMD 128
#define EPSV 1e-5f

typedef _Float16 f16;
typedef f16 f16x2 __attribute__((ext_vector_type(2)));
typedef f16 f16x8 __attribute__((ext_vector_type(8)));
typedef float f32x2 __attribute__((ext_vector_type(2)));
typedef float f32x4 __attribute__((ext_vector_type(4)));

// ---------------- edge-index dtype probe (int64 stored vs int32) ----------
__global__ void k_detect(const int* __restrict__ ei, int nchk, int* __restrict__ mode) {
    __shared__ int any;
    if (threadIdx.x == 0) any = 0;
    __syncthreads();
    for (int i = threadIdx.x; i < nchk; i += 256)
        if (ei[2 * i + 1] != 0) any = 1;   // benign race
    __syncthreads();
    if (threadIdx.x == 0) *mode = any ? 0 : 1;  // 1 => data is int64 pairs
}

__device__ __forceinline__ int load_src(const int* ei, int e, int E, int m) {
    return m ? ei[2 * e] : ei[e];
}
__device__ __forceinline__ int load_dst(const int* ei, int e, int E, int m) {
    return m ? ei[2 * (E + e)] : ei[E + e];
}

// ---------------- latent -> fp16 copy -------------------------------------
__global__ void k_prep(const float2* __restrict__ lat, f16x2* __restrict__ lat16,
                       int total2) {
    int i = blockIdx.x * 256 + threadIdx.x;
    if (i < total2) {
        float2 v = lat[i];
        f16x2 o = {(f16)v.x, (f16)v.y};
        lat16[i] = o;
    }
}

// ---------------- W0 -> f16 transposed: Wt[j][k] = W[k][j] ----------------
__global__ void k_w0(const float* __restrict__ W, f16* __restrict__ Wt) {
    int idx = blockIdx.x * 256 + threadIdx.x;  // 16384
    int j = idx >> 7, k = idx & 127;
    Wt[idx] = (f16)W[k * 128 + j];
}

// ---------------- rank + histogram (single atomic pass) --------------------
__global__ void k_rank(const int* __restrict__ ei, int* __restrict__ rank,
                       int* __restrict__ cnt, const int* __restrict__ modep, int E) {
    int e = blockIdx.x * 256 + threadIdx.x;
    if (e < E) {
        int m = *modep;
        int d = load_dst(ei, e, E, m);
        rank[e] = atomicAdd(&cnt[d], 1);
    }
}

// ---------------- 3-kernel exclusive scan of cnt -> offs -------------------
__global__ void k_scanA(const int* __restrict__ cnt, int* __restrict__ offs,
                        int* __restrict__ bsum, int N) {
    __shared__ int sh[256];
    int tid = threadIdx.x;
    int i = blockIdx.x * 256 + tid;
    int v = (i < N) ? cnt[i] : 0;
    sh[tid] = v;
    __syncthreads();
    for (int off = 1; off < 256; off <<= 1) {
        int t = (tid >= off) ? sh[tid - off] : 0;
        __syncthreads();
        sh[tid] += t;
        __syncthreads();
    }
    if (i < N) offs[i] = sh[tid] - v;  // exclusive
    if (tid == 255) bsum[blockIdx.x] = sh[255];
}

__global__ void k_scanB(int* __restrict__ bsum, int* __restrict__ bbase, int NB) {
    __shared__ int sh[256];
    int tid = threadIdx.x;
    int v = (tid < NB) ? bsum[tid] : 0;
    sh[tid] = v;
    __syncthreads();
    for (int off = 1; off < 256; off <<= 1) {
        int t = (tid >= off) ? sh[tid - off] : 0;
        __syncthreads();
        sh[tid] += t;
        __syncthreads();
    }
    if (tid < NB) bbase[tid] = sh[tid] - v;
}

__global__ void k_scanC(const int* __restrict__ cnt, int* __restrict__ offs,
                        const int* __restrict__ bbase, int N) {
    int i = blockIdx.x * 256 + threadIdx.x;
    if (i < N) {
        int v = offs[i] + bbase[blockIdx.x];
        offs[i] = v;
        if (i == N - 1) offs[N] = v + cnt[i];
    }
}

// ------- CSR fill (atomic-free): csr = {src, f32 w/16} --------------------
__global__ void k_fill(const int* __restrict__ ei, const float* __restrict__ ew,
                       const int* __restrict__ offs, const int* __restrict__ rank,
                       int2* __restrict__ csr, const int* __restrict__ modep, int E) {
    int e = blockIdx.x * 256 + threadIdx.x;
    if (e < E) {
        int m = *modep;
        int s = load_src(ei, e, E, m);
        int d = load_dst(ei, e, E, m);
        int pos = offs[d] + rank[e];
        csr[pos] = make_int2(s, __float_as_int(ew[e] * 0.0625f));
    }
}

// ---------------- degree from CSR (coalesced) -> dinv ----------------------
__global__ __launch_bounds__(256) void k_deg(const int2* __restrict__ csr,
                                             const int* __restrict__ offs,
                                             float* __restrict__ dinv, int N, int nwaves) {
    int lane = threadIdx.x & 63;
    int wid = blockIdx.x * 4 + (threadIdx.x >> 6);
    for (int n = wid; n < N; n += nwaves) {
        int kb = offs[n], ke = offs[n + 1];
        float s = 0.f;
        for (int e = kb + lane; e < ke; e += 64) s += __int_as_float(csr[e].y);
        for (int off = 32; off; off >>= 1) s += __shfl_down(s, off);
        if (lane == 0) dinv[n] = rsqrtf(16.0f * s + 1.0f);
    }
}

// --- MFMA GEMM 64-row (production layer 0; thrice-passing config) ---------
__global__ __launch_bounds__(256) void k_gemm_mfma(const f16x8* __restrict__ X,
                                                   const f16* __restrict__ Wt,
                                                   const float* __restrict__ cb,
                                                   const float* __restrict__ dinv,
                                                   unsigned* __restrict__ Y8, int N) {
    __shared__ __align__(16) char lds[32768];
    int tid = threadIdx.x;
#pragma unroll
    for (int it = 0; it < 8; ++it) {
        int c = tid + it * 256;
        int j = c >> 4, k16 = c & 15;
        int dst = j * 256 + ((k16 * 16) ^ ((j & 7) << 4));
        *(f16x8*)(lds + dst) = ((const f16x8*)Wt)[c];
    }
    __syncthreads();
    int lane = tid & 63;
    int wv = tid >> 6;
    int kq = lane >> 4;
    int mrow = blockIdx.x * 64 + wv * 16 + (lane & 15);
    int mc = mrow < N ? mrow : N - 1;
    f16x8 xf[4];
#pragma unroll
    for (int kt = 0; kt < 4; ++kt) xf[kt] = X[(size_t)mc * 16 + kt * 4 + kq];
    float dv = dinv[mc] * 16.0f;
    bool wr = (mrow < N);
#pragma unroll
    for (int jt = 0; jt < 8; ++jt) {
        f32x4 acc = {0.f, 0.f, 0.f, 0.f};
        int j = jt * 16 + (lane & 15);
        int rb = j * 256;
        int sw = (j & 7) << 4;
#pragma unroll
        for (int kt = 0; kt < 4; ++kt) {
            f16x8 wf = *(const f16x8*)(lds + rb + ((kt * 64 + kq * 16) ^ sw));
            acc = __builtin_amdgcn_mfma_f32_16x16x32_f16(wf, xf[kt], acc, 0, 0, 0);
        }
        float4 c4 = {0.f, 0.f, 0.f, 0.f};
        if (cb) c4 = ((const float4*)cb)[jt * 4 + kq];
        if (wr) {
            __hip_fp8x2_storage_t lo = __hip_cvt_float2_to_fp8x2(
                make_float2((acc[0] + c4.x) * dv, (acc[1] + c4.y) * dv),
                __HIP_SATFINITE, __HIP_E4M3);
            __hip_fp8x2_storage_t hi = __hip_cvt_float2_to_fp8x2(
                make_float2((acc[2] + c4.z) * dv, (acc[3] + c4.w) * dv),
                __HIP_SATFINITE, __HIP_E4M3);
            Y8[(size_t)mrow * 32 + jt * 4 + kq] = (unsigned)lo | ((unsigned)hi << 16);
        }
    }
}

// --- GEMM (VALU, production layers 1-2): y8 = fp8(16*dinv*(X16@W + cb)) ---
__global__ __launch_bounds__(256) void k_gemm(const f16x2* __restrict__ X16,
                                              const float* __restrict__ W,
                                              const float* __restrict__ cb,
                                              const float* __restrict__ dinv,
                                              unsigned* __restrict__ Y8, int N) {
    __shared__ float Wl[64 * 128];
    __shared__ float xl[8 * 64];
    int tid = threadIdx.x;
    int nl = tid >> 5, jg = tid & 31;
    int base = blockIdx.x * 8;
    float4 acc = {0.f, 0.f, 0.f, 0.f};
    for (int chunk = 0; chunk < 2; ++chunk) {
        int kc = chunk * 64;
        const float4* Wg = (const float4*)(W + (size_t)kc * 128);
#pragma unroll
        for (int r = 0; r < 8; r++) ((float4*)Wl)[r * 256 + tid] = Wg[r * 256 + tid];
        {
            int rr = tid >> 5;
            int kk = (tid & 31) * 2;
            int row = base + rr;
            float2 v = {0.f, 0.f};
            if (row < N) {
                f16x2 hv = X16[(size_t)row * 64 + (kc >> 1) + (tid & 31)];
                v.x = (float)hv.x;
                v.y = (float)hv.y;
            }
            xl[rr * 64 + kk] = v.x;
            xl[rr * 64 + kk + 1] = v.y;
        }
        __syncthreads();
#pragma unroll 8
        for (int k = 0; k < 64; k++) {
            float xv = xl[nl * 64 + k];
            float4 w4 = ((const float4*)Wl)[k * 32 + jg];
            acc.x += xv * w4.x;
            acc.y += xv * w4.y;
            acc.z += xv * w4.z;
            acc.w += xv * w4.w;
        }
        __syncthreads();
    }
    if (cb) {
        float4 c4 = ((const float4*)cb)[jg];
        acc.x += c4.x; acc.y += c4.y; acc.z += c4.z; acc.w += c4.w;
    }
    int n = base + nl;
    if (n < N) {
        float sc = dinv[n] * 16.0f;
        __hip_fp8x2_storage_t lo = __hip_cvt_float2_to_fp8x2(
            make_float2(acc.x * sc, acc.y * sc), __HIP_SATFINITE, __HIP_E4M3);
        __hip_fp8x2_storage_t hi = __hip_cvt_float2_to_fp8x2(
            make_float2(acc.z * sc, acc.w * sc), __HIP_SATFINITE, __HIP_E4M3);
        Y8[(size_t)n * 32 + jg] = (unsigned)lo | ((unsigned)hi << 16);
    }
}

// ------- aggregation: t = dinv*(sum w'*y8[src] + y8[n]/16) + b (...) ------
__global__ __launch_bounds__(256) void k_aggr(
    const unsigned short* __restrict__ y8, const f16x2* __restrict__ lat16,
    const int2* __restrict__ csr, const int* __restrict__ offs,
    const float* __restrict__ dinv, const float* __restrict__ bias,
    f16x2* __restrict__ T16, float* __restrict__ gsum, float* __restrict__ gsq,
    int N, int relu, int nwaves) {
    __shared__ float ssum[128], ssq[128];
    int tid = threadIdx.x;
    if (tid < 128) { ssum[tid] = 0.f; ssq[tid] = 0.f; }
    __syncthreads();
    unsigned lane = tid & 63;
    int wid = blockIdx.x * 4 + (tid >> 6);
    float2 b2 = ((const float2*)bias)[lane];
    float2 ts = {0.f, 0.f}, tq = {0.f, 0.f};
    for (int n = wid; n < N; n += nwaves) {
        int kb = offs[n], ke = offs[n + 1];
        float2 acc = {0.f, 0.f};
        for (int b0 = kb; b0 < ke; b0 += 64) {
            int e = b0 + (int)lane;
            int2 v = make_int2(0, 0);
            if (e < ke) v = csr[e];
            int cnt8 = (min(64, ke - b0) + 7) & ~7;  // wave-uniform
            for (int t0 = 0; t0 < cnt8; t0 += 8) {
#pragma unroll
                for (int u = 0; u < 8; u++) {
                    int t = t0 + u;
                    unsigned ss = (unsigned)__builtin_amdgcn_readlane(v.x, t);
                    float ww = __uint_as_float(
                        (unsigned)__builtin_amdgcn_readlane(v.y, t));
                    unsigned r = y8[(ss << 6) | lane];   // 32-bit voffset
                    f32x2 yv = __builtin_amdgcn_cvt_pk_f32_fp8(r, false);
                    acc.x += ww * yv.x;
                    acc.y += ww * yv.y;
                }
            }
        }
        f32x2 sv = __builtin_amdgcn_cvt_pk_f32_fp8(
            (unsigned)y8[((unsigned)n << 6) | lane], false);
        float dv = dinv[n];
        acc.x = (acc.x + 0.0625f * sv.x) * dv + b2.x;
        acc.y = (acc.y + 0.0625f * sv.y) * dv + b2.y;
        if (relu) { acc.x = fmaxf(acc.x, 0.f); acc.y = fmaxf(acc.y, 0.f); }
        f16x2 lv = lat16[((unsigned)n << 6) | lane];
        acc.x += (float)lv.x;
        acc.y += (float)lv.y;
        f16x2 to = {(f16)acc.x, (f16)acc.y};
        T16[((unsigned)n << 6) | lane] = to;
        ts.x += acc.x; ts.y += acc.y;
        tq.x += acc.x * acc.x; tq.y += acc.y * acc.y;
    }
    atomicAdd(&ssum[lane * 2], ts.x);
    atomicAdd(&ssum[lane * 2 + 1], ts.y);
    atomicAdd(&ssq[lane * 2], tq.x);
    atomicAdd(&ssq[lane * 2 + 1], tq.y);
    __syncthreads();
    if (tid < 128) {
        int copy = blockIdx.x & 31;
        atomicAdd(&gsum[copy * 128 + tid], ssum[tid]);
        atomicAdd(&gsq[copy * 128 + tid], ssq[tid]);
    }
}

// ------- fused BN stats + f32 folded Wf + cW ------------------------------
__global__ void k_post(const float* __restrict__ gsum, const float* __restrict__ gsq,
                       const float* __restrict__ gamma, const float* __restrict__ beta,
                       const float* __restrict__ W, float* __restrict__ A,
                       float* __restrict__ C, float* __restrict__ Wf,
                       float* __restrict__ cW, int N) {
    __shared__ float As[128], Cs[128];
    int tid = threadIdx.x;  // 256
    if (tid < 128) {
        float s = 0.f, q = 0.f;
        for (int c = 0; c < 32; c++) { s += gsum[c * 128 + tid]; q += gsq[c * 128 + tid]; }
        float mean = s / (float)N;
        float var = q / (float)N - mean * mean;
        float a = gamma[tid] * rsqrtf(var + EPSV);
        float cc = beta[tid] - a * mean;
        As[tid] = a; Cs[tid] = cc;
        A[tid] = a; C[tid] = cc;
    }
    __syncthreads();
    if (W) {
        for (int i4 = tid; i4 < 4096; i4 += 256) {
            int k = i4 >> 5;
            float a = As[k];
            float4 w = ((const float4*)W)[i4];
            float4 o;
            o.x = a * w.x; o.y = a * w.y; o.z = a * w.z; o.w = a * w.w;
            ((float4*)Wf)[i4] = o;
        }
        if (tid < 128) {
            float acc = 0.f;
            for (int k = 0; k < 128; k++) acc += Cs[k] * W[k * 128 + tid];
            cW[tid] = acc;
        }
    }
}

// ---------------- final normalize of layer-2 output ------------------------
__global__ void k_bnorm(const f16x2* __restrict__ T16, const float* __restrict__ A,
                        const float* __restrict__ C, float2* __restrict__ out, int total2) {
    int i = blockIdx.x * 256 + threadIdx.x;
    if (i < total2) {
        int c = i & 63;
        f16x2 t = T16[i];
        float2 a = ((const float2*)A)[c];
        float2 cc = ((const float2*)C)[c];
        float2 r;
        r.x = a.x * (float)t.x + cc.x;
        r.y = a.y * (float)t.y + cc.y;
        out[i] = r;
    }
}

extern "C" void kernel_launch(void* const* d_in, const int* in_sizes, int n_in,
                              void* d_out, int out_size, void* d_ws, size_t ws_size,
                              hipStream_t stream) {
    const float* latent = (const float*)d_in[0];
    const int* ei = (const int*)d_in[1];
    const float* ew = (const float*)d_in[2];
    const float* Ws = (const float*)d_in[3];
    const float* bs = (const float*)d_in[4];
    const float* gammas = (const float*)d_in[5];
    const float* betas = (const float*)d_in[6];
    float* out = (float*)d_out;

    const int N = in_sizes[0] / DIMD;
    const int E = in_sizes[1] / 2;
    const int NB = (N + 255) / 256;
    const int Npad = (N + 255) & ~255;

    char* p = (char*)d_ws;
    auto alloc = [&](size_t b) -> char* {
        char* r = p;
        p += (b + 255) & ~(size_t)255;
        return r;
    };
    // ---- zero-initialized region (must stay first & contiguous) ----
    int* cnt = (int*)alloc((size_t)Npad * 4);
    float* gstats = (float*)alloc((size_t)3 * 2 * 32 * 128 * 4);  // [layer][sum/sq][copy][j]
    size_t zbytes = (size_t)(p - (char*)d_ws);
    // ---- rest ----
    int* mode = (int*)alloc(256);
    float* dinv = (float*)alloc((size_t)N * 4);
    int* offs = (int*)alloc((size_t)(N + 1) * 4);
    int* bsum = (int*)alloc(256 * 4);
    int* bbase = (int*)alloc(256 * 4);
    float* A = (float*)alloc(128 * 4);
    float* C = (float*)alloc(128 * 4);
    float* cW = (float*)alloc(128 * 4);
    float* Wf = (float*)alloc((size_t)128 * 128 * 4);          // folded f32 weights (L1/L2)
    f16* Wt16 = (f16*)alloc((size_t)128 * 128 * 2);            // W0 transposed (layer-0 MFMA)
    int* rank = (int*)alloc((size_t)E * 4);
    int2* csr = (int2*)alloc((size_t)E * 8);
    unsigned* bufY8 = (unsigned*)alloc((size_t)N * DIMD);      // y (fp8 e4m3, x16)
    f16x2* lat16 = (f16x2*)alloc((size_t)N * DIMD * 2);        // latent (fp16)
    f16x2* bufB16 = (f16x2*)alloc((size_t)N * DIMD * 2);       // t (fp16)

    hipMemsetAsync(d_ws, 0, zbytes, stream);

    int nchk = E < 4096 ? E : 4096;
    int total2 = N * (DIMD / 2);
    k_detect<<<1, 256, 0, stream>>>(ei, nchk, mode);
    k_prep<<<(total2 + 255) / 256, 256, 0, stream>>>((const float2*)latent, lat16, total2);
    k_w0<<<64, 256, 0, stream>>>(Ws, Wt16);
    k_rank<<<(E + 255) / 256, 256, 0, stream>>>(ei, rank, cnt, mode, E);
    k_scanA<<<NB, 256, 0, stream>>>(cnt, offs, bsum, N);
    k_scanB<<<1, 256, 0, stream>>>(bsum, bbase, NB);
    k_scanC<<<NB, 256, 0, stream>>>(cnt, offs, bbase, N);
    k_fill<<<(E + 255) / 256, 256, 0, stream>>>(ei, ew, offs, rank, csr, mode, E);
    k_deg<<<512, 256, 0, stream>>>(csr, offs, dinv, N, 2048);

    const f16x2* gin = lat16;
    for (int i = 0; i < 3; i++) {
        if (i == 0) {
            k_gemm_mfma<<<(N + 63) / 64, 256, 0, stream>>>((const f16x8*)gin, Wt16,
                                                           nullptr, dinv, bufY8, N);
        } else {
            k_gemm<<<(N + 7) / 8, 256, 0, stream>>>(gin, Wf, cW, dinv, bufY8, N);
        }
        float* gsum_i = gstats + (size_t)i * 2 * 32 * 128;
        float* gsq_i = gsum_i + 32 * 128;
        k_aggr<<<2048, 256, 0, stream>>>((const unsigned short*)bufY8, lat16, csr, offs,
                                         dinv, bs + i * DIMD, bufB16, gsum_i, gsq_i, N,
                                         (i != 1) ? 1 : 0, 8192);
        const float* Wnext = (i < 2) ? (Ws + (size_t)(i + 1) * DIMD * DIMD) : nullptr;
        k_post<<<1, 256, 0, stream>>>(gsum_i, gsq_i, gammas + i * DIMD, betas + i * DIMD,
                                      Wnext, A, C, Wf, cW, N);
        if (i < 2) gin = bufB16;  // next GEMM consumes un-normalized t (fp16)
    }
    k_bnorm<<<(total2 + 255) / 256, 256, 0, stream>>>(bufB16, A, C, (float2*)out, total2);
}